// Round 13
// baseline (349.811 us; speedup 1.0000x reference)
//
#include <hip/hip_runtime.h>

// Problem constants (from reference setup_inputs)
constexpr int NN = 50000;   // nodes
constexpr int H  = 128;     // hidden
constexpr int F  = 256;     // input features
constexpr int C  = 40;      // classes

// graph-prepass partitioning: 8 ranges of 6400 nodes, 96 chunks.
// hist/fill blocks keep linear ids r + 8*b => range r pinned to XCD r.
constexpr int RSZ = 6400;
constexpr int NRG = 8;
constexpr int CH  = 96;     // chunks; also bytes/node in node-major partials

typedef short bf16x8 __attribute__((ext_vector_type(8)));
typedef float f32x4  __attribute__((ext_vector_type(4)));

__device__ inline unsigned short f2bf(float f) {          // RNE fp32 -> bf16
    unsigned u = __float_as_uint(f);
    u += 0x7fff + ((u >> 16) & 1);
    return (unsigned short)(u >> 16);
}
__device__ inline float bf2f(unsigned short s) {
    return __uint_as_float(((unsigned)s) << 16);
}
__device__ inline int bsum4(unsigned v) {
    return (v & 0xff) + ((v >> 8) & 0xff) + ((v >> 16) & 0xff) + (v >> 24);
}
// exclusive byte-prefix within one u32, carries `run`
__device__ inline unsigned prefix4(unsigned v, int& run) {
    unsigned p0 = (unsigned)run;
    unsigned p1 = p0 + (v & 0xff);
    unsigned p2 = p1 + ((v >> 8) & 0xff);
    unsigned p3 = p2 + ((v >> 16) & 0xff);
    run = (int)(p3 + (v >> 24));
    return p0 | (p1 << 8) | (p2 << 16) | (p3 << 24);
}

// ------------------------------------------------ GEMM body (shared device fn)
// C = A(fp32,[M,K]) @ B via hi/lo bf16 split (3 MFMA products), A split in-kernel.
// MODE 0: outf = acc + bias[gc] (gc < Nout mask);  MODE 1: outh = bf16(acc*row_scale)
template<int MODE, int BN>
__device__ __forceinline__ void gemm_body(
        int by,
        const float* __restrict__ A,
        const unsigned short* __restrict__ Bth, const unsigned short* __restrict__ Btl,
        const float* __restrict__ bias, const float* __restrict__ row_scale,
        float* __restrict__ outf, unsigned short* __restrict__ outh,
        int M, int Nout, int K) {
    constexpr int NT = BN / 64;
    __shared__ unsigned short As_h[4 * 65 * 8];
    __shared__ unsigned short As_l[4 * 65 * 8];
    __shared__ unsigned short Bs_h[4 * (BN + 1) * 8];
    __shared__ unsigned short Bs_l[4 * (BN + 1) * 8];

    const int tid  = threadIdx.x;
    const int wave = tid >> 6;
    const int lane = tid & 63;
    const int quad = lane >> 4;
    const int lr   = lane & 15;
    const int row0 = by * 64;
    const int wn0  = wave * (BN / 4);

    f32x4 acc[4][NT];
#pragma unroll
    for (int mt = 0; mt < 4; mt++)
#pragma unroll
        for (int nt = 0; nt < NT; nt++)
            acc[mt][nt] = (f32x4){0.f, 0.f, 0.f, 0.f};

    for (int k0 = 0; k0 < K; k0 += 32) {
#pragma unroll
        for (int r = 0; r < 2; r++) {
            int c   = tid + 256 * r;
            int row = c >> 3;
            int k4f = c & 7;
            int gr  = row0 + row;
            float4 v = make_float4(0.f, 0.f, 0.f, 0.f);
            if (gr < M) v = *(const float4*)&A[(long)gr * K + k0 + k4f * 4];
            unsigned short h0 = f2bf(v.x), h1 = f2bf(v.y), h2 = f2bf(v.z), h3 = f2bf(v.w);
            unsigned short l0 = f2bf(v.x - bf2f(h0));
            unsigned short l1 = f2bf(v.y - bf2f(h1));
            unsigned short l2 = f2bf(v.z - bf2f(h2));
            unsigned short l3 = f2bf(v.w - bf2f(h3));
            int base = (k4f >> 1) * 520 + row * 8 + (k4f & 1) * 4;
            ushort4 hv = make_ushort4(h0, h1, h2, h3);
            ushort4 lv = make_ushort4(l0, l1, l2, l3);
            *(ushort4*)&As_h[base] = hv;
            *(ushort4*)&As_l[base] = lv;
        }
        for (int c = tid; c < BN * 4; c += 256) {
            int n  = c >> 2;
            int k4 = c & 3;
            long off = (long)n * K + k0 + k4 * 8;
            uint4 vh = *(const uint4*)&Bth[off];
            uint4 vl = *(const uint4*)&Btl[off];
            int bbase = k4 * (BN + 1) * 8 + n * 8;
            *(uint4*)&Bs_h[bbase] = vh;
            *(uint4*)&Bs_l[bbase] = vl;
        }
        __syncthreads();

        bf16x8 ah[4], al[4], bh[NT], bl[NT];
#pragma unroll
        for (int mt = 0; mt < 4; mt++) {
            int ab = quad * 520 + (mt * 16 + lr) * 8;
            ah[mt] = *(const bf16x8*)&As_h[ab];
            al[mt] = *(const bf16x8*)&As_l[ab];
        }
#pragma unroll
        for (int nt = 0; nt < NT; nt++) {
            int bb = quad * (BN + 1) * 8 + (wn0 + nt * 16 + lr) * 8;
            bh[nt] = *(const bf16x8*)&Bs_h[bb];
            bl[nt] = *(const bf16x8*)&Bs_l[bb];
        }
#pragma unroll
        for (int mt = 0; mt < 4; mt++)
#pragma unroll
            for (int nt = 0; nt < NT; nt++) {
                acc[mt][nt] = __builtin_amdgcn_mfma_f32_16x16x32_bf16(ah[mt], bh[nt], acc[mt][nt], 0, 0, 0);
                acc[mt][nt] = __builtin_amdgcn_mfma_f32_16x16x32_bf16(al[mt], bh[nt], acc[mt][nt], 0, 0, 0);
                acc[mt][nt] = __builtin_amdgcn_mfma_f32_16x16x32_bf16(ah[mt], bl[nt], acc[mt][nt], 0, 0, 0);
            }
        __syncthreads();
    }

#pragma unroll
    for (int mt = 0; mt < 4; mt++) {
#pragma unroll
        for (int nt = 0; nt < NT; nt++) {
            int gc = wn0 + nt * 16 + lr;
#pragma unroll
            for (int r = 0; r < 4; r++) {
                int gr = row0 + mt * 16 + quad * 4 + r;
                if (gr >= M) continue;
                float v = acc[mt][nt][r];
                if (MODE == 0) {
                    if (gc < Nout) outf[(long)gr * Nout + gc] = v + bias[gc];
                } else {
                    outh[(long)gr * Nout + gc] = f2bf(v * row_scale[gr]);
                }
            }
        }
    }
}

// ------------------------------------------------ D1: hist (768) + weight prep (288)
// Partials node-major u8: p[node*96 + chunk]. Scattered 1-B writeout, absorbed
// by the XCD-local L2 (all chunks of range r are pinned to XCD r).
__global__ __launch_bounds__(256) void hist_prep(
        const int* __restrict__ src, const int* __restrict__ dst,
        unsigned char* __restrict__ p_out, unsigned char* __restrict__ p_in, int E,
        const float* __restrict__ Wp, const float* __restrict__ W1,
        const float* __restrict__ W2, const float* __restrict__ Wc,
        unsigned short* __restrict__ ph, unsigned short* __restrict__ pl,
        unsigned short* __restrict__ h1h, unsigned short* __restrict__ h1l,
        unsigned short* __restrict__ h2h, unsigned short* __restrict__ h2l,
        unsigned short* __restrict__ chh, unsigned short* __restrict__ cll) {
    __shared__ int ho[RSZ];
    __shared__ int hi[RSZ];
    const int t = threadIdx.x;
    if (blockIdx.x < NRG * CH) {
        const int r = blockIdx.x & 7;        // linear id = r + 8*b (XCD pinning)
        const int b = blockIdx.x >> 3;
        for (int i = t; i < RSZ; i += 256) { ho[i] = 0; hi[i] = 0; }
        __syncthreads();
        const int base = r * RSZ;
        const int CE = (E + CH - 1) / CH;
        const int e0 = b * CE, e1 = min(E, e0 + CE);
#pragma unroll 4
        for (int e = e0 + t; e < e1; e += 256) {
            int s = src[e], d = dst[e];
            unsigned so = (unsigned)(s - base);
            unsigned dof = (unsigned)(d - base);
            if (so < (unsigned)RSZ) atomicAdd(&ho[so], 1);
            if (dof < (unsigned)RSZ) atomicAdd(&hi[dof], 1);
        }
        __syncthreads();
        for (int i = t; i < RSZ; i += 256) {
            long a = ((long)(base + i)) * CH + b;
            p_out[a] = (unsigned char)ho[i];
            p_in[a]  = (unsigned char)hi[i];
        }
        return;
    }
    // weight transpose + hi/lo split (73728 elements over 288 blocks)
    int i = (blockIdx.x - NRG * CH) * 256 + t;
    const float* W; unsigned short *Bh, *Bl; int K, N, j;
    if (i < 32768)        { W = Wp; Bh = ph;  Bl = pl;  K = 256; N = 128; j = i; }
    else if (i < 49152)   { W = W1; Bh = h1h; Bl = h1l; K = 128; N = 128; j = i - 32768; }
    else if (i < 65536)   { W = W2; Bh = h2h; Bl = h2l; K = 128; N = 128; j = i - 49152; }
    else if (i < 73728)   { W = Wc; Bh = chh; Bl = cll; K = 128; N = 40;  j = i - 65536; }
    else return;
    int n = j / K, k = j % K;
    float v = (n < N) ? W[(long)k * N + n] : 0.f;
    unsigned short hh = f2bf(v);
    unsigned short ll = f2bf(v - bf2f(hh));
    Bh[(long)n * K + k] = hh;
    Bl[(long)n * K + k] = ll;
}

// ------------------------------------------------ D2: merge_scan (196) + proj GEMM (782)
// merge: per node, 6+6 contiguous uint4 loads of node-major u8 partials,
// in-register byte prefix, 6 uint4 stores. Latency chain ~2 rounds (was 96).
__global__ __launch_bounds__(256) void merge_proj(
        const unsigned char* __restrict__ p_out, unsigned char* __restrict__ p_in,
        int* __restrict__ cnt_in, float* __restrict__ rs_out, float* __restrict__ rs_in,
        int* __restrict__ row_start, int* __restrict__ block_sums, int n, int nb,
        const float* __restrict__ A,
        const unsigned short* __restrict__ Bth, const unsigned short* __restrict__ Btl,
        const float* __restrict__ bias, float* __restrict__ outf,
        int M, int Nout, int K) {
    if ((int)blockIdx.x < nb) {
        __shared__ int sh[256];
        const int t = threadIdx.x;
        const int i = blockIdx.x * 256 + t;
        int si = 0;
        if (i < n) {
            const long a = (long)i * CH;                 // 96 B per node, 16-aligned
            const uint4* po4 = (const uint4*)(p_out + a);
            uint4* pi4 = (uint4*)(p_in + a);
            uint4 o[6], w[6];
#pragma unroll
            for (int k = 0; k < 6; k++) o[k] = po4[k];
#pragma unroll
            for (int k = 0; k < 6; k++) w[k] = pi4[k];
            int so = 0;
#pragma unroll
            for (int k = 0; k < 6; k++)
                so += bsum4(o[k].x) + bsum4(o[k].y) + bsum4(o[k].z) + bsum4(o[k].w);
            int run = 0;
#pragma unroll
            for (int k = 0; k < 6; k++) {
                w[k].x = prefix4(w[k].x, run);
                w[k].y = prefix4(w[k].y, run);
                w[k].z = prefix4(w[k].z, run);
                w[k].w = prefix4(w[k].w, run);
            }
#pragma unroll
            for (int k = 0; k < 6; k++) pi4[k] = w[k];
            si = run;
            cnt_in[i] = si;
            rs_out[i] = rsqrtf((float)max(so, 1));
            rs_in[i]  = rsqrtf((float)max(si, 1));
        }
        sh[t] = si;
        __syncthreads();
#pragma unroll
        for (int off = 1; off < 256; off <<= 1) {
            int u = (t >= off) ? sh[t - off] : 0;
            __syncthreads();
            sh[t] += u;
            __syncthreads();
        }
        if (i < n) row_start[i] = sh[t] - si;
        if (t == 255) block_sums[blockIdx.x] = sh[255];
        return;
    }
    gemm_body<0, 128>(blockIdx.x - nb, A, Bth, Btl, bias, nullptr,
                      outf, nullptr, M, Nout, K);
}

// ------------------------------------------------ D3: scan_sums (1) + layer1 GEMM (782)
__global__ __launch_bounds__(256) void scansums_gemm(
        int* __restrict__ block_sums, int nb,
        const float* __restrict__ A,
        const unsigned short* __restrict__ Bth, const unsigned short* __restrict__ Btl,
        const float* __restrict__ row_scale, unsigned short* __restrict__ outh,
        int M, int Nout, int K) {
    if (blockIdx.x == 0) {
        __shared__ int sh[256];
        const int t = threadIdx.x;
        const int v = (t < nb) ? block_sums[t] : 0;
        sh[t] = v;
        __syncthreads();
#pragma unroll
        for (int off = 1; off < 256; off <<= 1) {
            int u = (t >= off) ? sh[t - off] : 0;
            __syncthreads();
            sh[t] += u;
            __syncthreads();
        }
        if (t < nb) block_sums[t] = sh[t] - v;
        return;
    }
    gemm_body<1, 128>(blockIdx.x - 1, A, Bth, Btl, nullptr, row_scale,
                      nullptr, outh, M, Nout, K);
}

// ------------------------------------------------ standalone GEMM wrapper
template<int MODE, int BN>
__global__ __launch_bounds__(256) void gemm_std(
        const float* __restrict__ A,
        const unsigned short* __restrict__ Bth, const unsigned short* __restrict__ Btl,
        const float* __restrict__ bias, const float* __restrict__ row_scale,
        float* __restrict__ outf, unsigned short* __restrict__ outh,
        int M, int Nout, int K) {
    gemm_body<MODE, BN>(blockIdx.x, A, Bth, Btl, bias, row_scale, outf, outh, M, Nout, K);
}

// ------------------------------------------------ D4: CSR fill with LDS cursors
__global__ __launch_bounds__(256) void fill_csr_part(
        const int* __restrict__ src, const int* __restrict__ dst,
        const int* __restrict__ row_start, const int* __restrict__ block_sums,
        const unsigned char* __restrict__ p_in,
        int* __restrict__ csr_src, int E, int n_nodes) {
    __shared__ int cur[RSZ];
    const int r = blockIdx.x;
    const int b = blockIdx.y;
    const int base = r * RSZ;
    for (int i = threadIdx.x; i < RSZ; i += 256) {
        int node = base + i;
        int rs = (node < n_nodes) ? (row_start[node] + block_sums[node >> 8]) : 0;
        cur[i] = rs + (int)p_in[(long)node * CH + b];
    }
    __syncthreads();
    const int CE = (E + CH - 1) / CH;
    const int e0 = b * CE, e1 = min(E, e0 + CE);
#pragma unroll 8
    for (int e = e0 + threadIdx.x; e < e1; e += 256) {
        int d = dst[e];
        unsigned dof = (unsigned)(d - base);
        if (dof < (unsigned)RSZ) {
            int pos = atomicAdd(&cur[dof], 1);   // LDS atomic
            csr_src[pos] = src[e];
        }
    }
}

// ---------------------------------------------------------------- aggregation (bf16 h)
__global__ __launch_bounds__(256) void aggregate_bf16(
        const uint4* __restrict__ h4, const int* __restrict__ csr_src,
        const int* __restrict__ row_start, const int* __restrict__ block_sums,
        const int* __restrict__ cnt_in,
        const float* __restrict__ rs_in, const float* __restrict__ bias,
        float* __restrict__ out, int nodes) {
    const int wave = threadIdx.x >> 6;
    const int lane = threadIdx.x & 63;
    const int grp  = lane >> 4;        // 0..3 = neighbor slot
    const int sl   = lane & 15;        // uint4 index in row
    const int v = blockIdx.x * 4 + wave;
    if (v >= nodes) return;
    const int s0  = row_start[v] + block_sums[v >> 8];
    const int cnt = cnt_in[v];

    float ax0 = 0.f, ay0 = 0.f, ax1 = 0.f, ay1 = 0.f;
    float ax2 = 0.f, ay2 = 0.f, ax3 = 0.f, ay3 = 0.f;
    int i0 = 0;
    for (; i0 + 8 <= cnt; i0 += 8) {               // 8 neighbors in flight
        int sA = csr_src[s0 + i0 + grp];
        int sB = csr_src[s0 + i0 + 4 + grp];
        uint4 uA = h4[(long)sA * 16 + sl];
        uint4 uB = h4[(long)sB * 16 + sl];
        ax0 += __uint_as_float(uA.x << 16) + __uint_as_float(uB.x << 16);
        ay0 += __uint_as_float(uA.x & 0xffff0000u) + __uint_as_float(uB.x & 0xffff0000u);
        ax1 += __uint_as_float(uA.y << 16) + __uint_as_float(uB.y << 16);
        ay1 += __uint_as_float(uA.y & 0xffff0000u) + __uint_as_float(uB.y & 0xffff0000u);
        ax2 += __uint_as_float(uA.z << 16) + __uint_as_float(uB.z << 16);
        ay2 += __uint_as_float(uA.z & 0xffff0000u) + __uint_as_float(uB.z & 0xffff0000u);
        ax3 += __uint_as_float(uA.w << 16) + __uint_as_float(uB.w << 16);
        ay3 += __uint_as_float(uA.w & 0xffff0000u) + __uint_as_float(uB.w & 0xffff0000u);
    }
    for (; i0 + 4 <= cnt; i0 += 4) {
        int s = csr_src[s0 + i0 + grp];
        uint4 u = h4[(long)s * 16 + sl];
        ax0 += __uint_as_float(u.x << 16); ay0 += __uint_as_float(u.x & 0xffff0000u);
        ax1 += __uint_as_float(u.y << 16); ay1 += __uint_as_float(u.y & 0xffff0000u);
        ax2 += __uint_as_float(u.z << 16); ay2 += __uint_as_float(u.z & 0xffff0000u);
        ax3 += __uint_as_float(u.w << 16); ay3 += __uint_as_float(u.w & 0xffff0000u);
    }
    if (i0 + grp < cnt) {                          // 0..3 tail neighbors
        int s = csr_src[s0 + i0 + grp];
        uint4 u = h4[(long)s * 16 + sl];
        ax0 += __uint_as_float(u.x << 16); ay0 += __uint_as_float(u.x & 0xffff0000u);
        ax1 += __uint_as_float(u.y << 16); ay1 += __uint_as_float(u.y & 0xffff0000u);
        ax2 += __uint_as_float(u.z << 16); ay2 += __uint_as_float(u.z & 0xffff0000u);
        ax3 += __uint_as_float(u.w << 16); ay3 += __uint_as_float(u.w & 0xffff0000u);
    }
    // sum across the 4 lane-groups (bits 4,5 of lane)
    ax0 += __shfl_xor(ax0, 16); ay0 += __shfl_xor(ay0, 16);
    ax1 += __shfl_xor(ax1, 16); ay1 += __shfl_xor(ay1, 16);
    ax2 += __shfl_xor(ax2, 16); ay2 += __shfl_xor(ay2, 16);
    ax3 += __shfl_xor(ax3, 16); ay3 += __shfl_xor(ay3, 16);
    ax0 += __shfl_xor(ax0, 32); ay0 += __shfl_xor(ay0, 32);
    ax1 += __shfl_xor(ax1, 32); ay1 += __shfl_xor(ay1, 32);
    ax2 += __shfl_xor(ax2, 32); ay2 += __shfl_xor(ay2, 32);
    ax3 += __shfl_xor(ax3, 32); ay3 += __shfl_xor(ay3, 32);

    if (grp == 0) {                                // lanes 0..15 store the row
        const float rs = rs_in[v];
        const float2 b0 = ((const float2*)bias)[sl * 4 + 0];
        const float2 b1 = ((const float2*)bias)[sl * 4 + 1];
        const float2 b2 = ((const float2*)bias)[sl * 4 + 2];
        const float2 b3 = ((const float2*)bias)[sl * 4 + 3];
        float4 o0, o1;
        o0.x = fmaxf(ax0 * rs + b0.x, 0.f); o0.y = fmaxf(ay0 * rs + b0.y, 0.f);
        o0.z = fmaxf(ax1 * rs + b1.x, 0.f); o0.w = fmaxf(ay1 * rs + b1.y, 0.f);
        o1.x = fmaxf(ax2 * rs + b2.x, 0.f); o1.y = fmaxf(ay2 * rs + b2.y, 0.f);
        o1.z = fmaxf(ax3 * rs + b3.x, 0.f); o1.w = fmaxf(ay3 * rs + b3.y, 0.f);
        float4* orow = (float4*)&out[(long)v * H];
        orow[sl * 2 + 0] = o0;
        orow[sl * 2 + 1] = o1;
    }
}

// ---------------------------------------------------------------- launch
extern "C" void kernel_launch(void* const* d_in, const int* in_sizes, int n_in,
                              void* d_out, int out_size, void* d_ws, size_t ws_size,
                              hipStream_t stream) {
    const float* n_feats = (const float*)d_in[0];
    const int*   src     = (const int*)d_in[1];
    const int*   dst     = (const int*)d_in[2];
    const float* Wp      = (const float*)d_in[3];
    const float* bp      = (const float*)d_in[4];
    const float* W1      = (const float*)d_in[5];
    const float* b1      = (const float*)d_in[6];
    const float* W2      = (const float*)d_in[7];
    const float* b2      = (const float*)d_in[8];
    const float* Wc      = (const float*)d_in[9];
    const float* bc      = (const float*)d_in[10];
    float* out = (float*)d_out;
    const int E = in_sizes[1];

    const long PSZB = (long)NRG * RSZ * CH;    // node-major u8 partials: 4.9 MB each

    // workspace layout (no aliasing; ~50 MB of 256 MiB)
    char* ws = (char*)d_ws;
    float*          xbuf  = (float*)ws;                             // NN*H fp32
    unsigned short* hbuf  = (unsigned short*)(xbuf + (long)NN * H); // NN*H bf16
    unsigned short* bt_ph = hbuf + (long)NN * H;                    // 128*256
    unsigned short* bt_pl = bt_ph + 128 * 256;
    unsigned short* bt_1h = bt_pl + 128 * 256;                      // 128*128
    unsigned short* bt_1l = bt_1h + 128 * 128;
    unsigned short* bt_2h = bt_1l + 128 * 128;
    unsigned short* bt_2l = bt_2h + 128 * 128;
    unsigned short* bt_ch = bt_2l + 128 * 128;                      // 64*128
    unsigned short* bt_cl = bt_ch + 64 * 128;
    int*   cnt_in     = (int*)(bt_cl + 64 * 128);                   // N
    int*   row_start  = cnt_in + NN;                                // N (within-block excl)
    float* rs_out     = (float*)(row_start + NN);                   // N
    float* rs_in      = rs_out + NN;                                // N
    int*   block_sums = (int*)(rs_in + NN);                         // 256
    unsigned char* p_out = (unsigned char*)(block_sums + 256);      // PSZB u8
    unsigned char* p_in  = p_out + PSZB;                            // PSZB u8
    int*   csr_src    = (int*)(p_in + PSZB);                        // E

    const int NB = (NN + 255) / 256;    // 196
    const int GB = (NN + 63) / 64;      // 782 GEMM row-blocks

    // D1: histograms (768, XCD-pinned ids) + weight prep (288)
    hist_prep<<<NRG * CH + 288, 256, 0, stream>>>(
        src, dst, p_out, p_in, E, Wp, W1, W2, Wc,
        bt_ph, bt_pl, bt_1h, bt_1l, bt_2h, bt_2l, bt_ch, bt_cl);
    // D2: merge+scan (196) + projection GEMM (782): xbuf = n_feats @ Wp + bp
    merge_proj<<<NB + GB, 256, 0, stream>>>(
        p_out, p_in, cnt_in, rs_out, rs_in, row_start, block_sums, NN, NB,
        n_feats, bt_ph, bt_pl, bp, xbuf, NN, H, F);
    // D3: scan of block sums (1) + layer-1 GEMM (782): hbuf = bf16((xbuf@W1)*rs_out)
    scansums_gemm<<<1 + GB, 256, 0, stream>>>(
        block_sums, NB, xbuf, bt_1h, bt_1l, rs_out, hbuf, NN, H, H);
    // D4: CSR fill (no global atomics)
    fill_csr_part<<<dim3(NRG, CH), 256, 0, stream>>>(
        src, dst, row_start, block_sums, p_in, csr_src, E, NN);
    // D5: aggregate 1 -> xbuf = relu(rs_in * (A hbuf) + b1)
    aggregate_bf16<<<(NN + 3) / 4, 256, 0, stream>>>(
        (const uint4*)hbuf, csr_src, row_start, block_sums, cnt_in, rs_in, b1, xbuf, NN);
    // D6: layer-2 GEMM
    gemm_std<1, 128><<<GB, 256, 0, stream>>>(
        xbuf, bt_2h, bt_2l, nullptr, rs_out, nullptr, hbuf, NN, H, H);
    // D7: aggregate 2
    aggregate_bf16<<<(NN + 3) / 4, 256, 0, stream>>>(
        (const uint4*)hbuf, csr_src, row_start, block_sums, cnt_in, rs_in, b2, xbuf, NN);
    // D8: classifier: out = xbuf @ Wc + bc (store-masked to 40 cols)
    gemm_std<0, 64><<<GB, 256, 0, stream>>>(
        xbuf, bt_ch, bt_cl, bc, nullptr, out, nullptr, NN, C, H);
}

// Round 14
// 281.134 us; speedup vs baseline: 1.2443x; 1.2443x over previous
//
#include <hip/hip_runtime.h>

// Problem constants (from reference setup_inputs)
constexpr int NN = 50000;   // nodes
constexpr int H  = 128;     // hidden
constexpr int F  = 256;     // input features
constexpr int C  = 40;      // classes

// graph-prepass partitioning: 8 ranges of 6400 nodes, 32 chunks, 1024-thread
// hist/fill blocks. hist linear ids 0..255: id%8 = range => XCD pinning.
constexpr int RSZ = 6400;
constexpr int NRG = 8;
constexpr int CHP = 32;     // partial chunks (merge chain length)

typedef short bf16x8 __attribute__((ext_vector_type(8)));
typedef float f32x4  __attribute__((ext_vector_type(4)));

__device__ inline unsigned short f2bf(float f) {          // RNE fp32 -> bf16
    unsigned u = __float_as_uint(f);
    u += 0x7fff + ((u >> 16) & 1);
    return (unsigned short)(u >> 16);
}
__device__ inline float bf2f(unsigned short s) {
    return __uint_as_float(((unsigned)s) << 16);
}

// ------------------------------------------------ GEMM body (shared device fn)
// C = A(fp32,[M,K]) @ B via hi/lo bf16 split (3 MFMA products), A split in-kernel.
// MODE 0: outf = acc + bias[gc] (gc < Nout mask);  MODE 1: outh = bf16(acc*row_scale)
template<int MODE, int BN>
__device__ __forceinline__ void gemm_body(
        int by,
        const float* __restrict__ A,
        const unsigned short* __restrict__ Bth, const unsigned short* __restrict__ Btl,
        const float* __restrict__ bias, const float* __restrict__ row_scale,
        float* __restrict__ outf, unsigned short* __restrict__ outh,
        int M, int Nout, int K) {
    constexpr int NT = BN / 64;
    __shared__ unsigned short As_h[4 * 65 * 8];
    __shared__ unsigned short As_l[4 * 65 * 8];
    __shared__ unsigned short Bs_h[4 * (BN + 1) * 8];
    __shared__ unsigned short Bs_l[4 * (BN + 1) * 8];

    const int tid  = threadIdx.x;
    const int wave = tid >> 6;
    const int lane = tid & 63;
    const int quad = lane >> 4;
    const int lr   = lane & 15;
    const int row0 = by * 64;
    const int wn0  = wave * (BN / 4);

    f32x4 acc[4][NT];
#pragma unroll
    for (int mt = 0; mt < 4; mt++)
#pragma unroll
        for (int nt = 0; nt < NT; nt++)
            acc[mt][nt] = (f32x4){0.f, 0.f, 0.f, 0.f};

    for (int k0 = 0; k0 < K; k0 += 32) {
#pragma unroll
        for (int r = 0; r < 2; r++) {
            int c   = tid + 256 * r;
            int row = c >> 3;
            int k4f = c & 7;
            int gr  = row0 + row;
            float4 v = make_float4(0.f, 0.f, 0.f, 0.f);
            if (gr < M) v = *(const float4*)&A[(long)gr * K + k0 + k4f * 4];
            unsigned short h0 = f2bf(v.x), h1 = f2bf(v.y), h2 = f2bf(v.z), h3 = f2bf(v.w);
            unsigned short l0 = f2bf(v.x - bf2f(h0));
            unsigned short l1 = f2bf(v.y - bf2f(h1));
            unsigned short l2 = f2bf(v.z - bf2f(h2));
            unsigned short l3 = f2bf(v.w - bf2f(h3));
            int base = (k4f >> 1) * 520 + row * 8 + (k4f & 1) * 4;
            ushort4 hv = make_ushort4(h0, h1, h2, h3);
            ushort4 lv = make_ushort4(l0, l1, l2, l3);
            *(ushort4*)&As_h[base] = hv;
            *(ushort4*)&As_l[base] = lv;
        }
        for (int c = tid; c < BN * 4; c += 256) {
            int n  = c >> 2;
            int k4 = c & 3;
            long off = (long)n * K + k0 + k4 * 8;
            uint4 vh = *(const uint4*)&Bth[off];
            uint4 vl = *(const uint4*)&Btl[off];
            int bbase = k4 * (BN + 1) * 8 + n * 8;
            *(uint4*)&Bs_h[bbase] = vh;
            *(uint4*)&Bs_l[bbase] = vl;
        }
        __syncthreads();

        bf16x8 ah[4], al[4], bh[NT], bl[NT];
#pragma unroll
        for (int mt = 0; mt < 4; mt++) {
            int ab = quad * 520 + (mt * 16 + lr) * 8;
            ah[mt] = *(const bf16x8*)&As_h[ab];
            al[mt] = *(const bf16x8*)&As_l[ab];
        }
#pragma unroll
        for (int nt = 0; nt < NT; nt++) {
            int bb = quad * (BN + 1) * 8 + (wn0 + nt * 16 + lr) * 8;
            bh[nt] = *(const bf16x8*)&Bs_h[bb];
            bl[nt] = *(const bf16x8*)&Bs_l[bb];
        }
#pragma unroll
        for (int mt = 0; mt < 4; mt++)
#pragma unroll
            for (int nt = 0; nt < NT; nt++) {
                acc[mt][nt] = __builtin_amdgcn_mfma_f32_16x16x32_bf16(ah[mt], bh[nt], acc[mt][nt], 0, 0, 0);
                acc[mt][nt] = __builtin_amdgcn_mfma_f32_16x16x32_bf16(al[mt], bh[nt], acc[mt][nt], 0, 0, 0);
                acc[mt][nt] = __builtin_amdgcn_mfma_f32_16x16x32_bf16(ah[mt], bl[nt], acc[mt][nt], 0, 0, 0);
            }
        __syncthreads();
    }

#pragma unroll
    for (int mt = 0; mt < 4; mt++) {
#pragma unroll
        for (int nt = 0; nt < NT; nt++) {
            int gc = wn0 + nt * 16 + lr;
#pragma unroll
            for (int r = 0; r < 4; r++) {
                int gr = row0 + mt * 16 + quad * 4 + r;
                if (gr >= M) continue;
                float v = acc[mt][nt][r];
                if (MODE == 0) {
                    if (gc < Nout) outf[(long)gr * Nout + gc] = v + bias[gc];
                } else {
                    outh[(long)gr * Nout + gc] = f2bf(v * row_scale[gr]);
                }
            }
        }
    }
}

// ------------------------------------------------ D1: hist (256 blocks) + prep (72)
// 1024 threads. Partials chunk-major u16 (coalesced writeout, packed pairs).
__global__ __launch_bounds__(1024) void hist_prep(
        const int* __restrict__ src, const int* __restrict__ dst,
        unsigned short* __restrict__ p_out, unsigned short* __restrict__ p_in, int E,
        const float* __restrict__ Wp, const float* __restrict__ W1,
        const float* __restrict__ W2, const float* __restrict__ Wc,
        unsigned short* __restrict__ ph, unsigned short* __restrict__ pl,
        unsigned short* __restrict__ h1h, unsigned short* __restrict__ h1l,
        unsigned short* __restrict__ h2h, unsigned short* __restrict__ h2l,
        unsigned short* __restrict__ chh, unsigned short* __restrict__ cll) {
    __shared__ int ho[RSZ];
    __shared__ int hi[RSZ];
    const int t = threadIdx.x;
    if (blockIdx.x < NRG * CHP) {
        const int r = blockIdx.x & 7;        // linear id = r + 8*b (XCD pinning)
        const int b = blockIdx.x >> 3;
        for (int i = t; i < RSZ; i += 1024) { ho[i] = 0; hi[i] = 0; }
        __syncthreads();
        const int base = r * RSZ;
        const int CE = (E + CHP - 1) / CHP;
        const int e0 = b * CE, e1 = min(E, e0 + CE);
#pragma unroll 4
        for (int e = e0 + t; e < e1; e += 1024) {
            int s = src[e], d = dst[e];
            unsigned so = (unsigned)(s - base);
            unsigned dof = (unsigned)(d - base);
            if (so < (unsigned)RSZ) atomicAdd(&ho[so], 1);
            if (dof < (unsigned)RSZ) atomicAdd(&hi[dof], 1);
        }
        __syncthreads();
        const long po = ((long)r * CHP + b) * RSZ;   // even
        unsigned* o32 = (unsigned*)&p_out[po];
        unsigned* i32 = (unsigned*)&p_in[po];
        for (int i = t; i < RSZ / 2; i += 1024) {
            o32[i] = (unsigned)ho[2 * i] | ((unsigned)ho[2 * i + 1] << 16);
            i32[i] = (unsigned)hi[2 * i] | ((unsigned)hi[2 * i + 1] << 16);
        }
        return;
    }
    // weight transpose + hi/lo split (73728 = 72 * 1024 elements)
    int i = (blockIdx.x - NRG * CHP) * 1024 + t;
    const float* W; unsigned short *Bh, *Bl; int K, N, j;
    if (i < 32768)        { W = Wp; Bh = ph;  Bl = pl;  K = 256; N = 128; j = i; }
    else if (i < 49152)   { W = W1; Bh = h1h; Bl = h1l; K = 128; N = 128; j = i - 32768; }
    else if (i < 65536)   { W = W2; Bh = h2h; Bl = h2l; K = 128; N = 128; j = i - 49152; }
    else if (i < 73728)   { W = Wc; Bh = chh; Bl = cll; K = 128; N = 40;  j = i - 65536; }
    else return;
    int n = j / K, k = j % K;
    float v = (n < N) ? W[(long)k * N + n] : 0.f;
    unsigned short hh = f2bf(v);
    unsigned short ll = f2bf(v - bf2f(hh));
    Bh[(long)n * K + k] = hh;
    Bl[(long)n * K + k] = ll;
}

// ------------------------------------------------ D2: merge_scan (196) + proj GEMM (782)
__global__ __launch_bounds__(256) void merge_proj(
        const unsigned short* __restrict__ p_out, unsigned short* __restrict__ p_in,
        int* __restrict__ cnt_in, float* __restrict__ rs_out, float* __restrict__ rs_in,
        int* __restrict__ row_start, int* __restrict__ block_sums, int n, int nb,
        const float* __restrict__ A,
        const unsigned short* __restrict__ Bth, const unsigned short* __restrict__ Btl,
        const float* __restrict__ bias, float* __restrict__ outf,
        int M, int Nout, int K) {
    if ((int)blockIdx.x < nb) {
        __shared__ int sh[256];
        const int t = threadIdx.x;
        const int i = blockIdx.x * 256 + t;
        int si = 0;
        if (i < n) {
            const int r = i / RSZ, off = i % RSZ;
            const long pb = (long)r * CHP * RSZ + off;
            int so = 0;
#pragma unroll 8
            for (int b = 0; b < CHP; b++) {
                so += p_out[pb + (long)b * RSZ];
                int v = p_in[pb + (long)b * RSZ];
                p_in[pb + (long)b * RSZ] = (unsigned short)si;
                si += v;
            }
            cnt_in[i] = si;
            rs_out[i] = rsqrtf((float)max(so, 1));
            rs_in[i]  = rsqrtf((float)max(si, 1));
        }
        sh[t] = si;
        __syncthreads();
#pragma unroll
        for (int off = 1; off < 256; off <<= 1) {
            int u = (t >= off) ? sh[t - off] : 0;
            __syncthreads();
            sh[t] += u;
            __syncthreads();
        }
        if (i < n) row_start[i] = sh[t] - si;
        if (t == 255) block_sums[blockIdx.x] = sh[255];
        return;
    }
    gemm_body<0, 128>(blockIdx.x - nb, A, Bth, Btl, bias, nullptr,
                      outf, nullptr, M, Nout, K);
}

// ------------------------------------------------ D3: scan_sums (1) + layer1 GEMM (782)
__global__ __launch_bounds__(256) void scansums_gemm(
        int* __restrict__ block_sums, int nb,
        const float* __restrict__ A,
        const unsigned short* __restrict__ Bth, const unsigned short* __restrict__ Btl,
        const float* __restrict__ row_scale, unsigned short* __restrict__ outh,
        int M, int Nout, int K) {
    if (blockIdx.x == 0) {
        __shared__ int sh[256];
        const int t = threadIdx.x;
        const int v = (t < nb) ? block_sums[t] : 0;
        sh[t] = v;
        __syncthreads();
#pragma unroll
        for (int off = 1; off < 256; off <<= 1) {
            int u = (t >= off) ? sh[t - off] : 0;
            __syncthreads();
            sh[t] += u;
            __syncthreads();
        }
        if (t < nb) block_sums[t] = sh[t] - v;
        return;
    }
    gemm_body<1, 128>(blockIdx.x - 1, A, Bth, Btl, nullptr, row_scale,
                      nullptr, outh, M, Nout, K);
}

// ------------------------------------------------ standalone GEMM wrapper
template<int MODE, int BN>
__global__ __launch_bounds__(256) void gemm_std(
        const float* __restrict__ A,
        const unsigned short* __restrict__ Bth, const unsigned short* __restrict__ Btl,
        const float* __restrict__ bias, const float* __restrict__ row_scale,
        float* __restrict__ outf, unsigned short* __restrict__ outh,
        int M, int Nout, int K) {
    gemm_body<MODE, BN>(blockIdx.x, A, Bth, Btl, bias, row_scale, outf, outh, M, Nout, K);
}

// ------------------------------------------------ D4: CSR fill, 1024 threads
__global__ __launch_bounds__(1024) void fill_csr_part(
        const int* __restrict__ src, const int* __restrict__ dst,
        const int* __restrict__ row_start, const int* __restrict__ block_sums,
        const unsigned short* __restrict__ p_in,
        int* __restrict__ csr_src, int E, int n_nodes) {
    __shared__ int cur[RSZ];
    const int r = blockIdx.x;
    const int b = blockIdx.y;
    const int base = r * RSZ;
    const long po = ((long)r * CHP + b) * RSZ;
    for (int i = threadIdx.x; i < RSZ; i += 1024) {
        int node = base + i;
        int rs = (node < n_nodes) ? (row_start[node] + block_sums[node >> 8]) : 0;
        cur[i] = rs + (int)p_in[po + i];
    }
    __syncthreads();
    const int CE = (E + CHP - 1) / CHP;
    const int e0 = b * CE, e1 = min(E, e0 + CE);
#pragma unroll 8
    for (int e = e0 + threadIdx.x; e < e1; e += 1024) {
        int d = dst[e];
        unsigned dof = (unsigned)(d - base);
        if (dof < (unsigned)RSZ) {
            int pos = atomicAdd(&cur[dof], 1);   // LDS atomic
            csr_src[pos] = src[e];
        }
    }
}

// ---------------------------------------------------------------- aggregation (bf16 h)
__global__ __launch_bounds__(256) void aggregate_bf16(
        const uint4* __restrict__ h4, const int* __restrict__ csr_src,
        const int* __restrict__ row_start, const int* __restrict__ block_sums,
        const int* __restrict__ cnt_in,
        const float* __restrict__ rs_in, const float* __restrict__ bias,
        float* __restrict__ out, int nodes) {
    const int wave = threadIdx.x >> 6;
    const int lane = threadIdx.x & 63;
    const int grp  = lane >> 4;        // 0..3 = neighbor slot
    const int sl   = lane & 15;        // uint4 index in row
    const int v = blockIdx.x * 4 + wave;
    if (v >= nodes) return;
    const int s0  = row_start[v] + block_sums[v >> 8];
    const int cnt = cnt_in[v];

    float ax0 = 0.f, ay0 = 0.f, ax1 = 0.f, ay1 = 0.f;
    float ax2 = 0.f, ay2 = 0.f, ax3 = 0.f, ay3 = 0.f;
    int i0 = 0;
    for (; i0 + 8 <= cnt; i0 += 8) {               // 8 neighbors in flight
        int sA = csr_src[s0 + i0 + grp];
        int sB = csr_src[s0 + i0 + 4 + grp];
        uint4 uA = h4[(long)sA * 16 + sl];
        uint4 uB = h4[(long)sB * 16 + sl];
        ax0 += __uint_as_float(uA.x << 16) + __uint_as_float(uB.x << 16);
        ay0 += __uint_as_float(uA.x & 0xffff0000u) + __uint_as_float(uB.x & 0xffff0000u);
        ax1 += __uint_as_float(uA.y << 16) + __uint_as_float(uB.y << 16);
        ay1 += __uint_as_float(uA.y & 0xffff0000u) + __uint_as_float(uB.y & 0xffff0000u);
        ax2 += __uint_as_float(uA.z << 16) + __uint_as_float(uB.z << 16);
        ay2 += __uint_as_float(uA.z & 0xffff0000u) + __uint_as_float(uB.z & 0xffff0000u);
        ax3 += __uint_as_float(uA.w << 16) + __uint_as_float(uB.w << 16);
        ay3 += __uint_as_float(uA.w & 0xffff0000u) + __uint_as_float(uB.w & 0xffff0000u);
    }
    for (; i0 + 4 <= cnt; i0 += 4) {
        int s = csr_src[s0 + i0 + grp];
        uint4 u = h4[(long)s * 16 + sl];
        ax0 += __uint_as_float(u.x << 16); ay0 += __uint_as_float(u.x & 0xffff0000u);
        ax1 += __uint_as_float(u.y << 16); ay1 += __uint_as_float(u.y & 0xffff0000u);
        ax2 += __uint_as_float(u.z << 16); ay2 += __uint_as_float(u.z & 0xffff0000u);
        ax3 += __uint_as_float(u.w << 16); ay3 += __uint_as_float(u.w & 0xffff0000u);
    }
    if (i0 + grp < cnt) {                          // 0..3 tail neighbors
        int s = csr_src[s0 + i0 + grp];
        uint4 u = h4[(long)s * 16 + sl];
        ax0 += __uint_as_float(u.x << 16); ay0 += __uint_as_float(u.x & 0xffff0000u);
        ax1 += __uint_as_float(u.y << 16); ay1 += __uint_as_float(u.y & 0xffff0000u);
        ax2 += __uint_as_float(u.z << 16); ay2 += __uint_as_float(u.z & 0xffff0000u);
        ax3 += __uint_as_float(u.w << 16); ay3 += __uint_as_float(u.w & 0xffff0000u);
    }
    // sum across the 4 lane-groups (bits 4,5 of lane)
    ax0 += __shfl_xor(ax0, 16); ay0 += __shfl_xor(ay0, 16);
    ax1 += __shfl_xor(ax1, 16); ay1 += __shfl_xor(ay1, 16);
    ax2 += __shfl_xor(ax2, 16); ay2 += __shfl_xor(ay2, 16);
    ax3 += __shfl_xor(ax3, 16); ay3 += __shfl_xor(ay3, 16);
    ax0 += __shfl_xor(ax0, 32); ay0 += __shfl_xor(ay0, 32);
    ax1 += __shfl_xor(ax1, 32); ay1 += __shfl_xor(ay1, 32);
    ax2 += __shfl_xor(ax2, 32); ay2 += __shfl_xor(ay2, 32);
    ax3 += __shfl_xor(ax3, 32); ay3 += __shfl_xor(ay3, 32);

    if (grp == 0) {                                // lanes 0..15 store the row
        const float rs = rs_in[v];
        const float2 b0 = ((const float2*)bias)[sl * 4 + 0];
        const float2 b1 = ((const float2*)bias)[sl * 4 + 1];
        const float2 b2 = ((const float2*)bias)[sl * 4 + 2];
        const float2 b3 = ((const float2*)bias)[sl * 4 + 3];
        float4 o0, o1;
        o0.x = fmaxf(ax0 * rs + b0.x, 0.f); o0.y = fmaxf(ay0 * rs + b0.y, 0.f);
        o0.z = fmaxf(ax1 * rs + b1.x, 0.f); o0.w = fmaxf(ay1 * rs + b1.y, 0.f);
        o1.x = fmaxf(ax2 * rs + b2.x, 0.f); o1.y = fmaxf(ay2 * rs + b2.y, 0.f);
        o1.z = fmaxf(ax3 * rs + b3.x, 0.f); o1.w = fmaxf(ay3 * rs + b3.y, 0.f);
        float4* orow = (float4*)&out[(long)v * H];
        orow[sl * 2 + 0] = o0;
        orow[sl * 2 + 1] = o1;
    }
}

// ---------------------------------------------------------------- launch
extern "C" void kernel_launch(void* const* d_in, const int* in_sizes, int n_in,
                              void* d_out, int out_size, void* d_ws, size_t ws_size,
                              hipStream_t stream) {
    const float* n_feats = (const float*)d_in[0];
    const int*   src     = (const int*)d_in[1];
    const int*   dst     = (const int*)d_in[2];
    const float* Wp      = (const float*)d_in[3];
    const float* bp      = (const float*)d_in[4];
    const float* W1      = (const float*)d_in[5];
    const float* b1      = (const float*)d_in[6];
    const float* W2      = (const float*)d_in[7];
    const float* b2      = (const float*)d_in[8];
    const float* Wc      = (const float*)d_in[9];
    const float* bc      = (const float*)d_in[10];
    float* out = (float*)d_out;
    const int E = in_sizes[1];

    const long PSZ = (long)NRG * CHP * RSZ;    // partials: 1,638,400 u16 (3.28 MB)

    // workspace layout (no aliasing; ~45 MB of 256 MiB)
    char* ws = (char*)d_ws;
    float*          xbuf  = (float*)ws;                             // NN*H fp32
    unsigned short* hbuf  = (unsigned short*)(xbuf + (long)NN * H); // NN*H bf16
    unsigned short* bt_ph = hbuf + (long)NN * H;                    // 128*256
    unsigned short* bt_pl = bt_ph + 128 * 256;
    unsigned short* bt_1h = bt_pl + 128 * 256;                      // 128*128
    unsigned short* bt_1l = bt_1h + 128 * 128;
    unsigned short* bt_2h = bt_1l + 128 * 128;
    unsigned short* bt_2l = bt_2h + 128 * 128;
    unsigned short* bt_ch = bt_2l + 128 * 128;                      // 64*128
    unsigned short* bt_cl = bt_ch + 64 * 128;
    int*   cnt_in     = (int*)(bt_cl + 64 * 128);                   // N
    int*   row_start  = cnt_in + NN;                                // N (within-block excl)
    float* rs_out     = (float*)(row_start + NN);                   // N
    float* rs_in      = rs_out + NN;                                // N
    int*   block_sums = (int*)(rs_in + NN);                         // 256
    unsigned short* p_out = (unsigned short*)(block_sums + 256);    // PSZ u16
    unsigned short* p_in  = p_out + PSZ;                            // PSZ u16
    int*   csr_src    = (int*)(p_in + PSZ);                         // E

    const int NB = (NN + 255) / 256;    // 196
    const int GB = (NN + 63) / 64;      // 782 GEMM row-blocks

    // D1: histograms (256 blocks, XCD-pinned) + weight prep (72), 1024 threads
    hist_prep<<<NRG * CHP + 72, 1024, 0, stream>>>(
        src, dst, p_out, p_in, E, Wp, W1, W2, Wc,
        bt_ph, bt_pl, bt_1h, bt_1l, bt_2h, bt_2l, bt_ch, bt_cl);
    // D2: merge+scan (196) + projection GEMM (782): xbuf = n_feats @ Wp + bp
    merge_proj<<<NB + GB, 256, 0, stream>>>(
        p_out, p_in, cnt_in, rs_out, rs_in, row_start, block_sums, NN, NB,
        n_feats, bt_ph, bt_pl, bp, xbuf, NN, H, F);
    // D3: scan of block sums (1) + layer-1 GEMM (782): hbuf = bf16((xbuf@W1)*rs_out)
    scansums_gemm<<<1 + GB, 256, 0, stream>>>(
        block_sums, NB, xbuf, bt_1h, bt_1l, rs_out, hbuf, NN, H, H);
    // D4: CSR fill (no global atomics), 1024 threads
    fill_csr_part<<<dim3(NRG, CHP), 1024, 0, stream>>>(
        src, dst, row_start, block_sums, p_in, csr_src, E, NN);
    // D5: aggregate 1 -> xbuf = relu(rs_in * (A hbuf) + b1)
    aggregate_bf16<<<(NN + 3) / 4, 256, 0, stream>>>(
        (const uint4*)hbuf, csr_src, row_start, block_sums, cnt_in, rs_in, b1, xbuf, NN);
    // D6: layer-2 GEMM
    gemm_std<1, 128><<<GB, 256, 0, stream>>>(
        xbuf, bt_2h, bt_2l, nullptr, rs_out, nullptr, hbuf, NN, H, H);
    // D7: aggregate 2
    aggregate_bf16<<<(NN + 3) / 4, 256, 0, stream>>>(
        (const uint4*)hbuf, csr_src, row_start, block_sums, cnt_in, rs_in, b2, xbuf, NN);
    // D8: classifier: out = xbuf @ Wc + bc (store-masked to 40 cols)
    gemm_std<0, 64><<<GB, 256, 0, stream>>>(
        xbuf, bt_ch, bt_cl, bc, nullptr, out, nullptr, NN, C, H);
}